// Round 22
// baseline (275.152 us; speedup 1.0000x reference)
//
#include <hip/hip_runtime.h>

typedef __bf16 bf16x8 __attribute__((ext_vector_type(8)));
typedef __bf16 bf16x4 __attribute__((ext_vector_type(4)));
typedef float f32x4 __attribute__((ext_vector_type(4)));
typedef unsigned short u16;
typedef unsigned int u32;

typedef union { bf16x8 v8; bf16x4 v4[2]; } bfu;

__device__ __forceinline__ u16 f2bf(float f) {
  u32 u = __builtin_bit_cast(u32, f);
  u = (u + 0x7FFFu + ((u >> 16) & 1u)) >> 16;
  return (u16)u;
}

__device__ __forceinline__ void gload_lds16(const void* g, void* l) {
  __builtin_amdgcn_global_load_lds((const __attribute__((address_space(1))) void*)g,
                                   (__attribute__((address_space(3))) void*)l, 16, 0, 0);
}

// ---------------------------------------------------------------------------
// Transpose + cast (batched): z = b(0..7) | which(0..2)<<3.
// ---------------------------------------------------------------------------
__global__ __launch_bounds__(256) void transpose_cast3(const float* __restrict__ q,
                                                       const float* __restrict__ k,
                                                       const float* __restrict__ v,
                                                       u16* __restrict__ X3) {
  __shared__ float T[64][68];
  int tid = threadIdx.x;
  int n0 = blockIdx.x * 64, i0 = blockIdx.y * 64;
  int z = blockIdx.z;
  int which = z >> 3, b = z & 7;
  const float* src = (which == 0) ? q : (which == 1) ? k : v;
  size_t boff = (size_t)b << 20;
  const float* s = src + boff;
  u16* d = X3 + ((size_t)which << 23) + boff;
  int ir = tid >> 4, n4 = (tid & 15) * 4;
#pragma unroll
  for (int r = 0; r < 4; ++r) {
    int i_loc = ir + r * 16;
    float4 vv = *(const float4*)(s + (size_t)(i0 + i_loc) * 1024 + n0 + n4);
    *(float4*)&T[i_loc][n4] = vv;
  }
  __syncthreads();
  int nr = tid >> 3, i8 = (tid & 7) * 8;
#pragma unroll
  for (int r = 0; r < 2; ++r) {
    int n_loc = nr + r * 32;
    u32 pk[4];
#pragma unroll
    for (int j = 0; j < 4; ++j) {
      float f0 = T[i8 + 2 * j][n_loc];
      float f1 = T[i8 + 2 * j + 1][n_loc];
      pk[j] = (u32)f2bf(f0) | ((u32)f2bf(f1) << 16);
    }
    *(uint4*)(d + (size_t)(n0 + n_loc) * 1024 + i0 + i8) = make_uint4(pk[0], pk[1], pk[2], pk[3]);
  }
}

__global__ __launch_bounds__(256) void transpose_cast(const float* __restrict__ src,
                                                      u16* __restrict__ dst) {
  __shared__ float T[64][68];
  int tid = threadIdx.x;
  int n0 = blockIdx.x * 64, i0 = blockIdx.y * 64;
  size_t boff = (size_t)blockIdx.z << 20;
  const float* s = src + boff;
  u16* d = dst + boff;
  int ir = tid >> 4, n4 = (tid & 15) * 4;
#pragma unroll
  for (int r = 0; r < 4; ++r) {
    int i_loc = ir + r * 16;
    float4 v = *(const float4*)(s + (size_t)(i0 + i_loc) * 1024 + n0 + n4);
    *(float4*)&T[i_loc][n4] = v;
  }
  __syncthreads();
  int nr = tid >> 3, i8 = (tid & 7) * 8;
#pragma unroll
  for (int r = 0; r < 2; ++r) {
    int n_loc = nr + r * 32;
    u32 pk[4];
#pragma unroll
    for (int j = 0; j < 4; ++j) {
      float f0 = T[i8 + 2 * j][n_loc];
      float f1 = T[i8 + 2 * j + 1][n_loc];
      pk[j] = (u32)f2bf(f0) | ((u32)f2bf(f1) << 16);
    }
    *(uint4*)(d + (size_t)(n0 + n_loc) * 1024 + i0 + i8) = make_uint4(pk[0], pk[1], pk[2], pk[3]);
  }
}

// ---------------------------------------------------------------------------
// Cast weights to bf16. w=0..2: Wq/Wk/Wv as-is. w=3: Wm' column-permuted.
// ---------------------------------------------------------------------------
__global__ __launch_bounds__(256) void cast_weights(const float* __restrict__ Wq,
                                                    const float* __restrict__ Wk,
                                                    const float* __restrict__ Wv,
                                                    const float* __restrict__ Wm,
                                                    u16* __restrict__ out) {
  int w = blockIdx.y;
  const float* src = (w == 0) ? Wq : (w == 1) ? Wk : (w == 2) ? Wv : Wm;
  u16* dst = out + ((size_t)w << 20);
  int o = blockIdx.x;
  int c4 = threadIdx.x * 4;
  float f[4];
  if (w < 3) {
    float4 v = *(const float4*)(src + (size_t)o * 1024 + c4);
    f[0] = v.x; f[1] = v.y; f[2] = v.z; f[3] = v.w;
  } else {
#pragma unroll
    for (int j = 0; j < 4; ++j) {
      int cp = c4 + j;
      f[j] = src[(size_t)o * 1024 + (cp & 63) * 16 + (cp >> 6)];
    }
  }
  u32 p0 = (u32)f2bf(f[0]) | ((u32)f2bf(f[1]) << 16);
  u32 p1 = (u32)f2bf(f[2]) | ((u32)f2bf(f[3]) << 16);
  *(uint2*)(dst + (size_t)o * 1024 + c4) = make_uint2(p0, p1);
}

// ---------------------------------------------------------------------------
// GEMM (r18, fallback path only).
// ---------------------------------------------------------------------------
__device__ __forceinline__ void gemm_body(const u16* __restrict__ A,
                                          const u16* __restrict__ B,
                                          const float* __restrict__ bias,
                                          void* __restrict__ Out, float escale,
                                          int epi, u16* LD) {
  int tid = threadIdx.x;
  int wave = tid >> 6, l = tid & 63, ln = l & 15, g = l >> 4;
  int wm = wave >> 1, wn = wave & 1;
  int bid = blockIdx.x;
  int mt = (bid >> 3) & 7;
  int nt = ((bid & 7) << 2) | (bid >> 6);
  int c0 = mt * 128, n0 = nt * 256;

  int R = tid >> 3;
  int v = (tid & 7) ^ (R & 7);
  const u16* aS = A + (size_t)(c0 + 2 * R + (v >> 2)) * 1024 + (v & 3) * 8;
  const u16* bS = B + (size_t)(n0 + 2 * R + (v >> 2)) * 1024 + (v & 3) * 8;

  int slr = ((((ln & 1) << 2) | g) ^ ((ln >> 1) & 7)) * 8;
  int laneA = (wm * 32 + (ln >> 1)) * 64 + slr;
  int laneB = (wn * 64 + (ln >> 1)) * 64 + slr;

  f32x4 acc[4][8] = {};

#define STAGE(buf, kt)                                                        \
  do {                                                                        \
    gload_lds16(aS + (kt) * 32, &LD[(buf) * 4096 + tid * 8]);                 \
    gload_lds16(aS + 65536 + (kt) * 32, &LD[(buf) * 4096 + 2048 + tid * 8]);  \
    gload_lds16(bS + (kt) * 32, &LD[12288 + (buf) * 8192 + tid * 8]);         \
    gload_lds16(bS + 65536 + (kt) * 32,                                       \
                &LD[12288 + (buf) * 8192 + 2048 + tid * 8]);                  \
    gload_lds16(bS + 131072 + (kt) * 32,                                      \
                &LD[12288 + (buf) * 8192 + 4096 + tid * 8]);                  \
    gload_lds16(bS + 196608 + (kt) * 32,                                      \
                &LD[12288 + (buf) * 8192 + 6144 + tid * 8]);                  \
  } while (0)

  STAGE(0, 0);
  STAGE(1, 1);

#pragma unroll
  for (int t = 0; t < 32; ++t) {
    if (t < 31)
      asm volatile("s_waitcnt vmcnt(6)" ::: "memory");
    else
      asm volatile("s_waitcnt vmcnt(0)" ::: "memory");
    asm volatile("s_barrier" ::: "memory");
    if (t <= 29) STAGE((t + 2) % 3, t + 2);
    const int ab = (t % 3) * 4096;
    const int bb = 12288 + (t % 3) * 8192;
    bf16x8 af[4];
#pragma unroll
    for (int mm = 0; mm < 4; ++mm) af[mm] = *(const bf16x8*)&LD[ab + laneA + mm * 512];
    __builtin_amdgcn_s_setprio(1);
#pragma unroll
    for (int nn = 0; nn < 8; ++nn) {
      bf16x8 bfr = *(const bf16x8*)&LD[bb + laneB + nn * 512];
#pragma unroll
      for (int mm = 0; mm < 4; ++mm)
        acc[mm][nn] = __builtin_amdgcn_mfma_f32_16x16x32_bf16(af[mm], bfr, acc[mm][nn], 0, 0, 0);
    }
    __builtin_amdgcn_s_setprio(0);
  }
#undef STAGE

  int D0 = (c0 >> 4) + wm * 4;
#pragma unroll
  for (int nn = 0; nn < 8; ++nn) {
    size_t ng = (size_t)n0 + wn * 128 + nn * 16 + ln;
#pragma unroll
    for (int r = 0; r < 4; ++r) {
      int h = g * 4 + r;
      if (epi == 0) {
        bf16x4 pk;
#pragma unroll
        for (int mm = 0; mm < 4; ++mm) {
          int c = c0 + wm * 64 + mm * 16 + h;
          pk[mm] = (__bf16)((acc[mm][nn][r] + bias[c]) * escale);
        }
        *(bf16x4*)((u16*)Out + ng * 1024 + (size_t)h * 64 + D0) = pk;
      } else {
        size_t b = ng >> 10, n = ng & 1023;
#pragma unroll
        for (int mm = 0; mm < 4; ++mm) {
          int c = c0 + wm * 64 + mm * 16 + h;
          float val = (acc[mm][nn][r] + bias[c]) * escale;
          if (epi == 1) {
            int d = D0 + mm;
            ((u16*)Out)[((b * 16 + h) * 64 + d) * 1024 + n] = f2bf(val);
          } else {
            ((float*)Out)[(b << 20) + (size_t)c * 1024 + n] = val;
          }
        }
      }
    }
  }
}

template <int EPI>
__global__ __launch_bounds__(256, 2) void gemm4b(const u16* __restrict__ A,
                                                 const u16* __restrict__ B,
                                                 const float* __restrict__ bias,
                                                 void* __restrict__ Out, float escale) {
  __shared__ u16 LD[36864];  // 72 KB
  gemm_body(A, B, bias, Out, escale, EPI, LD);
}

// ---------------------------------------------------------------------------
// Split-K GEMM body: tile 256(M)x128(N), BK=64, 8 waves = 2M x 2N x 2K.
// Each wave: 128x64 output sub-tile over HALF of K (kk = wave&1): fragment
// traffic 12 KB / 32 MFMA (fat-wave ratio 0.375) AND 256 blocks/slice (even
// generations). 3 LDS buffers (144 KB), 1 barrier + vmcnt(6) per K-tile,
// STAGE post-barrier into (t+2)%3. Swizzle slot^=(row&7) both-sides.
// Epilogue: partner waves (wave^1) exchange the nn-half they don't own via
// LDS (reused buffer space; lane stride 65 f32x4 -> conflict-free), add,
// and each stores its owned nn pair.
// XCD map: xcd=bid&7 owns 8 contiguous nt x all 4 mt.
// epi 0: bf16 -> Q/K [ng][h][d]; 1: bf16 -> V [b][h][d][n]; 2: fp32 [b][c][n].
// grid 256 x 512 threads per slice.
// ---------------------------------------------------------------------------
__device__ __forceinline__ void gemm_kk_body(const u16* __restrict__ A,
                                             const u16* __restrict__ B,
                                             const float* __restrict__ bias,
                                             void* __restrict__ Out, float escale,
                                             int epi, u16* LD) {
  int tid = threadIdx.x;
  int wave = tid >> 6, l = tid & 63, ln = l & 15, g = l >> 4;
  int kkw = wave & 1, wn = (wave >> 1) & 1, wm = wave >> 2;
  int bid = blockIdx.x;
  int j = bid >> 3;
  int mt = j & 3;
  int nt = (bid & 7) * 8 + (j >> 2);
  int c0 = mt * 256, n0 = nt * 128;

  // staging: thread -> row r0 (+64/128/192 for A, +64 for B), swizzled 16B col
  int r0 = tid >> 3, sl = tid & 7;
  int scol = (sl ^ (r0 & 7)) * 8;
  const u16* aS = A + (size_t)(c0 + r0) * 1024 + scol;
  const u16* bS = B + (size_t)(n0 + r0) * 1024 + scol;
  int dst0 = tid * 8;

  // fragment reads: row X, slot (kkw*4+g) ^ (X&7); X&7 == ln&7 for our rows
  int swr = (((kkw << 2) | g) ^ (ln & 7)) * 8;
  int laneA = (wm * 128 + ln) * 64 + swr;   // + m*1024 + bufA*16384
  int laneB = (wn * 64 + ln) * 64 + swr;    // + nn*1024 + 49152 + bufB*8192

  f32x4 acc[8][4] = {};

#define STGA(kt, buf)                                                     \
  do {                                                                    \
    const u16* s_ = aS + (kt) * 64;                                       \
    int d_ = (buf) * 16384 + dst0;                                        \
    gload_lds16(s_, &LD[d_]);                                             \
    gload_lds16(s_ + 65536, &LD[d_ + 4096]);                              \
    gload_lds16(s_ + 131072, &LD[d_ + 8192]);                             \
    gload_lds16(s_ + 196608, &LD[d_ + 12288]);                            \
  } while (0)
#define STGB(kt, buf)                                                     \
  do {                                                                    \
    const u16* s_ = bS + (kt) * 64;                                       \
    int d_ = 49152 + (buf) * 8192 + dst0;                                 \
    gload_lds16(s_, &LD[d_]);                                             \
    gload_lds16(s_ + 65536, &LD[d_ + 4096]);                              \
  } while (0)

  // prologue: tiles 0 and 1 (12 loads)
  STGA(0, 0);
  STGB(0, 0);
  STGA(1, 1);
  STGB(1, 1);

#pragma unroll
  for (int t = 0; t < 16; ++t) {
    if (t < 15)
      asm volatile("s_waitcnt vmcnt(6)" ::: "memory");
    else
      asm volatile("s_waitcnt vmcnt(0)" ::: "memory");
    asm volatile("s_barrier" ::: "memory");
    const int ab = (t % 3) * 16384;
    const int bb = 49152 + (t % 3) * 8192;
    bf16x8 af[4], bfr[4];
    // phase 0: m 0-3
#pragma unroll
    for (int m = 0; m < 4; ++m) af[m] = *(const bf16x8*)&LD[ab + laneA + m * 1024];
#pragma unroll
    for (int nn = 0; nn < 4; ++nn) bfr[nn] = *(const bf16x8*)&LD[bb + laneB + nn * 1024];
    if (t <= 13) STGA(t + 2, (t + 2) % 3);
    __builtin_amdgcn_s_setprio(1);
#pragma unroll
    for (int m = 0; m < 4; ++m)
#pragma unroll
      for (int nn = 0; nn < 4; ++nn)
        acc[m][nn] = __builtin_amdgcn_mfma_f32_16x16x32_bf16(af[m], bfr[nn], acc[m][nn], 0, 0, 0);
    __builtin_amdgcn_s_setprio(0);
    // phase 1: m 4-7 (B reused)
#pragma unroll
    for (int m = 0; m < 4; ++m) af[m] = *(const bf16x8*)&LD[ab + laneA + (m + 4) * 1024];
    if (t <= 13) STGB(t + 2, (t + 2) % 3);
    __builtin_amdgcn_s_setprio(1);
#pragma unroll
    for (int m = 0; m < 4; ++m)
#pragma unroll
      for (int nn = 0; nn < 4; ++nn)
        acc[m + 4][nn] = __builtin_amdgcn_mfma_f32_16x16x32_bf16(af[m], bfr[nn], acc[m + 4][nn], 0, 0, 0);
    __builtin_amdgcn_s_setprio(0);
  }
#undef STGA
#undef STGB

  // ---- cross-kk reduction: wave kkw owns nn in {2kkw, 2kkw+1} ----
  float* LDf = (float*)LD;
  int mybase = wave * 4160 + l * 65;            // f32 units; 65-stride = bank-free
  int pbase = (wave ^ 1) * 4160 + l * 65;
  __syncthreads();
#pragma unroll
  for (int m = 0; m < 8; ++m)
#pragma unroll
    for (int p = 0; p < 2; ++p) {
      int nn = 2 * (1 - kkw) + p;
      *(f32x4*)&LDf[mybase + (m * 2 + p) * 4] = acc[m][nn];
    }
  __syncthreads();
#pragma unroll
  for (int m = 0; m < 8; ++m)
#pragma unroll
    for (int p = 0; p < 2; ++p) {
      int nn = 2 * kkw + p;
      f32x4 v = *(const f32x4*)&LDf[pbase + (m * 2 + p) * 4];
      acc[m][nn][0] += v[0]; acc[m][nn][1] += v[1];
      acc[m][nn][2] += v[2]; acc[m][nn][3] += v[3];
    }

  int D0 = (c0 >> 4) + wm * 8;
#pragma unroll
  for (int p = 0; p < 2; ++p) {
    int nn = 2 * kkw + p;
    size_t ng = (size_t)n0 + wn * 64 + nn * 16 + ln;
#pragma unroll
    for (int r = 0; r < 4; ++r) {
      int h = g * 4 + r;
      if (epi == 0) {
        bf16x8 pk;
#pragma unroll
        for (int m = 0; m < 8; ++m) {
          int c = c0 + wm * 128 + m * 16 + h;
          pk[m] = (__bf16)((acc[m][nn][r] + bias[c]) * escale);
        }
        *(bf16x8*)((u16*)Out + ng * 1024 + (size_t)h * 64 + D0) = pk;
      } else {
        size_t b = ng >> 10, n = ng & 1023;
#pragma unroll
        for (int m = 0; m < 8; ++m) {
          int c = c0 + wm * 128 + m * 16 + h;
          float val = (acc[m][nn][r] + bias[c]) * escale;
          if (epi == 1) {
            int d = D0 + m;
            ((u16*)Out)[((b * 16 + h) * 64 + d) * 1024 + n] = f2bf(val);
          } else {
            ((float*)Out)[(b << 20) + (size_t)c * 1024 + n] = val;
          }
        }
      }
    }
  }
}

// QKV: grid (256, 3) x 512 threads; z selects weight/input/output/epi.
__global__ __launch_bounds__(512, 1) void gemm_qkvs(const u16* __restrict__ Wbf,
                                                    const u16* __restrict__ X3,
                                                    const float* __restrict__ bq,
                                                    const float* __restrict__ bk,
                                                    const float* __restrict__ bv,
                                                    u16* __restrict__ Qh,
                                                    u16* __restrict__ Kh,
                                                    u16* __restrict__ Vt, float qscale) {
  __shared__ u16 LD[73728];  // 144 KB
  int z = blockIdx.y;
  const u16* A = Wbf + ((size_t)z << 20);
  const u16* B = X3 + ((size_t)z << 23);
  const float* bias = (z == 0) ? bq : (z == 1) ? bk : bv;
  void* Out = (z == 0) ? (void*)Qh : (z == 1) ? (void*)Kh : (void*)Vt;
  float escale = (z == 0) ? qscale : 1.0f;
  int epi = (z == 2) ? 1 : 0;
  gemm_kk_body(A, B, bias, Out, escale, epi, LD);
}

// Final projection: grid 256 x 512 threads, epi 2.
__global__ __launch_bounds__(512, 1) void gemm_fs(const u16* __restrict__ A,
                                                  const u16* __restrict__ B,
                                                  const float* __restrict__ bias,
                                                  void* __restrict__ Out) {
  __shared__ u16 LD[73728];  // 144 KB
  gemm_kk_body(A, B, bias, Out, 1.0f, 2, LD);
}

// ---------------------------------------------------------------------------
// Flash attention v5 (r17 winner, unchanged): one block = (b,h, 256 q-rows),
// register-P. Q,K in [b][n][h][d], V in [b][h][d][n]. Output [b][n][h*64+d].
// ---------------------------------------------------------------------------
__global__ __launch_bounds__(256, 2) void attn_kernel(const u16* __restrict__ Qh,
                                                      const u16* __restrict__ Kh,
                                                      const u16* __restrict__ Vt,
                                                      u16* __restrict__ Xh) {
  __shared__ u16 Ks[2][4096];
  __shared__ u16 Vs[2][4096];
  int tid = threadIdx.x;
  int w = tid >> 6, l = tid & 63, ln = l & 15, g = l >> 4;
  int id = blockIdx.x;
  int bh7 = id & 7;
  int qp = (id >> 3) & 3;
  int bh = (id >> 5) * 8 + bh7;
  size_t b = bh >> 4;
  int h = bh & 15;
  const u16* Qg = Qh + (b << 20) + (h << 6);
  const u16* Kg = Kh + (b << 20) + (h << 6);
  const u16* Vg = Vt + ((size_t)bh << 16);
  u16* Og = Xh + (b << 20) + (h << 6);

  bf16x8 qf[4][2];
#pragma unroll
  for (int t = 0; t < 4; ++t)
#pragma unroll
    for (int kk = 0; kk < 2; ++kk)
      qf[t][kk] = *(const bf16x8*)(Qg + (size_t)(qp * 256 + t * 64 + w * 16 + ln) * 1024 + kk * 32 + g * 8);

  int lr = l >> 3;
  int sw8 = ((l & 7) ^ lr) << 3;
  int r0 = w * 16 + lr, r1 = r0 + 8;
  const u16* kS0 = Kg + (size_t)r0 * 1024 + sw8;
  const u16* kS1 = Kg + (size_t)r1 * 1024 + sw8;
  const u16* vS0 = Vg + (size_t)r0 * 1024 + sw8;
  const u16* vS1 = Vg + (size_t)r1 * 1024 + sw8;

  f32x4 xacc[4][4] = {};
  float lacc[4] = {0.f, 0.f, 0.f, 0.f};

  gload_lds16(kS0, &Ks[0][(w * 2) * 512]);
  gload_lds16(kS1, &Ks[0][(w * 2 + 1) * 512]);
  gload_lds16(vS0, &Vs[0][(w * 2) * 512]);
  gload_lds16(vS1, &Vs[0][(w * 2 + 1) * 512]);
  __syncthreads();

  int sx = ln & 7;
  int cur = 0;
  for (int kt = 0; kt < 16; ++kt) {
    if (kt < 15) {
      int nxt = cur ^ 1;
      gload_lds16(kS0 + (size_t)(kt + 1) * 65536, &Ks[nxt][(w * 2) * 512]);
      gload_lds16(kS1 + (size_t)(kt + 1) * 65536, &Ks[nxt][(w * 2 + 1) * 512]);
      gload_lds16(vS0 + (kt + 1) * 64, &Vs[nxt][(w * 2) * 512]);
      gload_lds16(vS1 + (kt + 1) * 64, &Vs[nxt][(w * 2 + 1) * 512]);
    }
    bf16x8 kf[2][4];
#pragma unroll
    for (int kk = 0; kk < 2; ++kk)
#pragma unroll
      for (int f = 0; f < 4; ++f) {
        int slot = (((kk << 2) + g) ^ sx) << 3;
        kf[kk][f] = *(const bf16x8*)&Ks[cur][(f * 16 + ln) * 64 + slot];
      }
    bf16x8 vf[2][4];
#pragma unroll
    for (int kk = 0; kk < 2; ++kk) {
      int s0 = (kk << 2) + (g >> 1);
      int off = (g & 1) << 2;
#pragma unroll
      for (int fd = 0; fd < 4; ++fd) {
        int rowb = (fd * 16 + ln) * 64;
        bfu uv;
        uv.v4[0] = *(const bf16x4*)&Vs[cur][rowb + ((s0 ^ sx) << 3) + off];
        uv.v4[1] = *(const bf16x4*)&Vs[cur][rowb + (((s0 + 2) ^ sx) << 3) + off];
        vf[kk][fd] = uv.v8;
      }
    }
#pragma unroll
    for (int t = 0; t < 4; ++t) {
      f32x4 sacc[4] = {};
#pragma unroll
      for (int kk = 0; kk < 2; ++kk)
#pragma unroll
        for (int f = 0; f < 4; ++f)
          sacc[f] = __builtin_amdgcn_mfma_f32_16x16x32_bf16(kf[kk][f], qf[t][kk], sacc[f], 0, 0, 0);
      bf16x8 pf[2];
#pragma unroll
      for (int kk = 0; kk < 2; ++kk) {
        bfu up;
#pragma unroll
        for (int e2 = 0; e2 < 2; ++e2) {
          int f = 2 * kk + e2;
          float p0 = __builtin_amdgcn_exp2f(sacc[f][0]);
          float p1 = __builtin_amdgcn_exp2f(sacc[f][1]);
          float p2 = __builtin_amdgcn_exp2f(sacc[f][2]);
          float p3 = __builtin_amdgcn_exp2f(sacc[f][3]);
          lacc[t] += (p0 + p1) + (p2 + p3);
          bf16x4 pb;
          pb[0] = (__bf16)p0; pb[1] = (__bf16)p1; pb[2] = (__bf16)p2; pb[3] = (__bf16)p3;
          up.v4[e2] = pb;
        }
        pf[kk] = up.v8;
      }
#pragma unroll
      for (int kk = 0; kk < 2; ++kk)
#pragma unroll
        for (int fd = 0; fd < 4; ++fd)
          xacc[t][fd] = __builtin_amdgcn_mfma_f32_16x16x32_bf16(pf[kk], vf[kk][fd], xacc[t][fd], 0, 0, 0);
    }
    __syncthreads();
    cur ^= 1;
  }

#pragma unroll
  for (int t = 0; t < 4; ++t) {
    float lt = lacc[t];
    lt += __shfl_xor(lt, 16);
    lt += __shfl_xor(lt, 32);
    float il[4];
#pragma unroll
    for (int r = 0; r < 4; ++r) il[r] = 1.0f / __shfl(lt, g * 4 + r);
#pragma unroll
    for (int fd = 0; fd < 4; ++fd)
#pragma unroll
      for (int r = 0; r < 4; ++r) {
        int nq = qp * 256 + t * 64 + w * 16 + g * 4 + r;
        Og[(size_t)nq * 1024 + fd * 16 + ln] = f2bf(xacc[t][fd][r] * il[r]);
      }
  }
}

// ---------------------------------------------------------------------------
extern "C" void kernel_launch(void* const* d_in, const int* in_sizes, int n_in,
                              void* d_out, int out_size, void* d_ws, size_t ws_size,
                              hipStream_t stream) {
  const float* q  = (const float*)d_in[0];
  const float* k  = (const float*)d_in[1];
  const float* v  = (const float*)d_in[2];
  const float* Wq = (const float*)d_in[3];
  const float* bq = (const float*)d_in[4];
  const float* Wk = (const float*)d_in[5];
  const float* bk = (const float*)d_in[6];
  const float* Wv = (const float*)d_in[7];
  const float* bv = (const float*)d_in[8];
  const float* Wm = (const float*)d_in[9];
  const float* bm = (const float*)d_in[10];

  char* ws = (char*)d_ws;
  u16* Wbf = (u16*)ws;                      //  8 MB: Wq,Wk,Wv,Wm' bf16
  u16* Qh  = (u16*)(ws + (8ull << 20));     // 16 MB [b][n][h][d]
  u16* Kh  = (u16*)(ws + (24ull << 20));    // 16 MB [b][n][h][d]
  u16* Vt  = (u16*)(ws + (40ull << 20));    // 16 MB [b][h][d][n]
  u16* X3  = (u16*)(ws + (56ull << 20));    // 16 or 48 MB (X^T bufs; attn out)

  cast_weights<<<dim3(1024, 4, 1), 256, 0, stream>>>(Wq, Wk, Wv, Wm, Wbf);

  const float qscale = 0.125f * 1.44269504088896340736f;  // 1/sqrt(64) * log2(e)

  if (ws_size >= (104ull << 20)) {
    transpose_cast3<<<dim3(16, 16, 24), 256, 0, stream>>>(q, k, v, X3);
    gemm_qkvs<<<dim3(256, 3), 512, 0, stream>>>(Wbf, X3, bq, bk, bv, Qh, Kh, Vt, qscale);
    attn_kernel<<<512, 256, 0, stream>>>(Qh, Kh, Vt, X3);
    gemm_fs<<<256, 512, 0, stream>>>(Wbf + (3u << 20), X3, bm, d_out);
  } else {
    dim3 tg(16, 16, 8);
    transpose_cast<<<tg, 256, 0, stream>>>(q, X3);
    gemm4b<0><<<256, 256, 0, stream>>>(Wbf, X3, bq, Qh, qscale);
    transpose_cast<<<tg, 256, 0, stream>>>(k, X3);
    gemm4b<0><<<256, 256, 0, stream>>>(Wbf + (1u << 20), X3, bk, Kh, 1.0f);
    transpose_cast<<<tg, 256, 0, stream>>>(v, X3);
    gemm4b<1><<<256, 256, 0, stream>>>(Wbf + (2u << 20), X3, bv, Vt, 1.0f);
    attn_kernel<<<512, 256, 0, stream>>>(Qh, Kh, Vt, X3);
    gemm4b<2><<<256, 256, 0, stream>>>(Wbf + (3u << 20), X3, bm, d_out, 1.0f);
  }
}

// Round 23
// 182.697 us; speedup vs baseline: 1.5061x; 1.5061x over previous
//
#include <hip/hip_runtime.h>

typedef __bf16 bf16x8 __attribute__((ext_vector_type(8)));
typedef __bf16 bf16x4 __attribute__((ext_vector_type(4)));
typedef float f32x4 __attribute__((ext_vector_type(4)));
typedef unsigned short u16;
typedef unsigned int u32;

typedef union { bf16x8 v8; bf16x4 v4[2]; } bfu;

__device__ __forceinline__ u16 f2bf(float f) {
  u32 u = __builtin_bit_cast(u32, f);
  u = (u + 0x7FFFu + ((u >> 16) & 1u)) >> 16;
  return (u16)u;
}

__device__ __forceinline__ void gload_lds16(const void* g, void* l) {
  __builtin_amdgcn_global_load_lds((const __attribute__((address_space(1))) void*)g,
                                   (__attribute__((address_space(3))) void*)l, 16, 0, 0);
}

// ---------------------------------------------------------------------------
// Transpose + cast (batched): z = b(0..7) | which(0..2)<<3.
// ---------------------------------------------------------------------------
__global__ __launch_bounds__(256) void transpose_cast3(const float* __restrict__ q,
                                                       const float* __restrict__ k,
                                                       const float* __restrict__ v,
                                                       u16* __restrict__ X3) {
  __shared__ float T[64][68];
  int tid = threadIdx.x;
  int n0 = blockIdx.x * 64, i0 = blockIdx.y * 64;
  int z = blockIdx.z;
  int which = z >> 3, b = z & 7;
  const float* src = (which == 0) ? q : (which == 1) ? k : v;
  size_t boff = (size_t)b << 20;
  const float* s = src + boff;
  u16* d = X3 + ((size_t)which << 23) + boff;
  int ir = tid >> 4, n4 = (tid & 15) * 4;
#pragma unroll
  for (int r = 0; r < 4; ++r) {
    int i_loc = ir + r * 16;
    float4 vv = *(const float4*)(s + (size_t)(i0 + i_loc) * 1024 + n0 + n4);
    *(float4*)&T[i_loc][n4] = vv;
  }
  __syncthreads();
  int nr = tid >> 3, i8 = (tid & 7) * 8;
#pragma unroll
  for (int r = 0; r < 2; ++r) {
    int n_loc = nr + r * 32;
    u32 pk[4];
#pragma unroll
    for (int j = 0; j < 4; ++j) {
      float f0 = T[i8 + 2 * j][n_loc];
      float f1 = T[i8 + 2 * j + 1][n_loc];
      pk[j] = (u32)f2bf(f0) | ((u32)f2bf(f1) << 16);
    }
    *(uint4*)(d + (size_t)(n0 + n_loc) * 1024 + i0 + i8) = make_uint4(pk[0], pk[1], pk[2], pk[3]);
  }
}

__global__ __launch_bounds__(256) void transpose_cast(const float* __restrict__ src,
                                                      u16* __restrict__ dst) {
  __shared__ float T[64][68];
  int tid = threadIdx.x;
  int n0 = blockIdx.x * 64, i0 = blockIdx.y * 64;
  size_t boff = (size_t)blockIdx.z << 20;
  const float* s = src + boff;
  u16* d = dst + boff;
  int ir = tid >> 4, n4 = (tid & 15) * 4;
#pragma unroll
  for (int r = 0; r < 4; ++r) {
    int i_loc = ir + r * 16;
    float4 v = *(const float4*)(s + (size_t)(i0 + i_loc) * 1024 + n0 + n4);
    *(float4*)&T[i_loc][n4] = v;
  }
  __syncthreads();
  int nr = tid >> 3, i8 = (tid & 7) * 8;
#pragma unroll
  for (int r = 0; r < 2; ++r) {
    int n_loc = nr + r * 32;
    u32 pk[4];
#pragma unroll
    for (int j = 0; j < 4; ++j) {
      float f0 = T[i8 + 2 * j][n_loc];
      float f1 = T[i8 + 2 * j + 1][n_loc];
      pk[j] = (u32)f2bf(f0) | ((u32)f2bf(f1) << 16);
    }
    *(uint4*)(d + (size_t)(n0 + n_loc) * 1024 + i0 + i8) = make_uint4(pk[0], pk[1], pk[2], pk[3]);
  }
}

// ---------------------------------------------------------------------------
// Cast weights to bf16. w=0..2: Wq/Wk/Wv as-is. w=3: Wm' column-permuted.
// ---------------------------------------------------------------------------
__global__ __launch_bounds__(256) void cast_weights(const float* __restrict__ Wq,
                                                    const float* __restrict__ Wk,
                                                    const float* __restrict__ Wv,
                                                    const float* __restrict__ Wm,
                                                    u16* __restrict__ out) {
  int w = blockIdx.y;
  const float* src = (w == 0) ? Wq : (w == 1) ? Wk : (w == 2) ? Wv : Wm;
  u16* dst = out + ((size_t)w << 20);
  int o = blockIdx.x;
  int c4 = threadIdx.x * 4;
  float f[4];
  if (w < 3) {
    float4 v = *(const float4*)(src + (size_t)o * 1024 + c4);
    f[0] = v.x; f[1] = v.y; f[2] = v.z; f[3] = v.w;
  } else {
#pragma unroll
    for (int j = 0; j < 4; ++j) {
      int cp = c4 + j;
      f[j] = src[(size_t)o * 1024 + (cp & 63) * 16 + (cp >> 6)];
    }
  }
  u32 p0 = (u32)f2bf(f[0]) | ((u32)f2bf(f[1]) << 16);
  u32 p1 = (u32)f2bf(f[2]) | ((u32)f2bf(f[3]) << 16);
  *(uint2*)(dst + (size_t)o * 1024 + c4) = make_uint2(p0, p1);
}

// ---------------------------------------------------------------------------
// GEMM (r18, fallback path only).
// ---------------------------------------------------------------------------
__device__ __forceinline__ void gemm_body(const u16* __restrict__ A,
                                          const u16* __restrict__ B,
                                          const float* __restrict__ bias,
                                          void* __restrict__ Out, float escale,
                                          int epi, u16* LD) {
  int tid = threadIdx.x;
  int wave = tid >> 6, l = tid & 63, ln = l & 15, g = l >> 4;
  int wm = wave >> 1, wn = wave & 1;
  int bid = blockIdx.x;
  int mt = (bid >> 3) & 7;
  int nt = ((bid & 7) << 2) | (bid >> 6);
  int c0 = mt * 128, n0 = nt * 256;

  int R = tid >> 3;
  int v = (tid & 7) ^ (R & 7);
  const u16* aS = A + (size_t)(c0 + 2 * R + (v >> 2)) * 1024 + (v & 3) * 8;
  const u16* bS = B + (size_t)(n0 + 2 * R + (v >> 2)) * 1024 + (v & 3) * 8;

  int slr = ((((ln & 1) << 2) | g) ^ ((ln >> 1) & 7)) * 8;
  int laneA = (wm * 32 + (ln >> 1)) * 64 + slr;
  int laneB = (wn * 64 + (ln >> 1)) * 64 + slr;

  f32x4 acc[4][8] = {};

#define STAGE(buf, kt)                                                        \
  do {                                                                        \
    gload_lds16(aS + (kt) * 32, &LD[(buf) * 4096 + tid * 8]);                 \
    gload_lds16(aS + 65536 + (kt) * 32, &LD[(buf) * 4096 + 2048 + tid * 8]);  \
    gload_lds16(bS + (kt) * 32, &LD[12288 + (buf) * 8192 + tid * 8]);         \
    gload_lds16(bS + 65536 + (kt) * 32,                                       \
                &LD[12288 + (buf) * 8192 + 2048 + tid * 8]);                  \
    gload_lds16(bS + 131072 + (kt) * 32,                                      \
                &LD[12288 + (buf) * 8192 + 4096 + tid * 8]);                  \
    gload_lds16(bS + 196608 + (kt) * 32,                                      \
                &LD[12288 + (buf) * 8192 + 6144 + tid * 8]);                  \
  } while (0)

  STAGE(0, 0);
  STAGE(1, 1);

#pragma unroll
  for (int t = 0; t < 32; ++t) {
    if (t < 31)
      asm volatile("s_waitcnt vmcnt(6)" ::: "memory");
    else
      asm volatile("s_waitcnt vmcnt(0)" ::: "memory");
    asm volatile("s_barrier" ::: "memory");
    if (t <= 29) STAGE((t + 2) % 3, t + 2);
    const int ab = (t % 3) * 4096;
    const int bb = 12288 + (t % 3) * 8192;
    bf16x8 af[4];
#pragma unroll
    for (int mm = 0; mm < 4; ++mm) af[mm] = *(const bf16x8*)&LD[ab + laneA + mm * 512];
    __builtin_amdgcn_s_setprio(1);
#pragma unroll
    for (int nn = 0; nn < 8; ++nn) {
      bf16x8 bfr = *(const bf16x8*)&LD[bb + laneB + nn * 512];
#pragma unroll
      for (int mm = 0; mm < 4; ++mm)
        acc[mm][nn] = __builtin_amdgcn_mfma_f32_16x16x32_bf16(af[mm], bfr, acc[mm][nn], 0, 0, 0);
    }
    __builtin_amdgcn_s_setprio(0);
  }
#undef STAGE

  int D0 = (c0 >> 4) + wm * 4;
#pragma unroll
  for (int nn = 0; nn < 8; ++nn) {
    size_t ng = (size_t)n0 + wn * 128 + nn * 16 + ln;
#pragma unroll
    for (int r = 0; r < 4; ++r) {
      int h = g * 4 + r;
      if (epi == 0) {
        bf16x4 pk;
#pragma unroll
        for (int mm = 0; mm < 4; ++mm) {
          int c = c0 + wm * 64 + mm * 16 + h;
          pk[mm] = (__bf16)((acc[mm][nn][r] + bias[c]) * escale);
        }
        *(bf16x4*)((u16*)Out + ng * 1024 + (size_t)h * 64 + D0) = pk;
      } else {
        size_t b = ng >> 10, n = ng & 1023;
#pragma unroll
        for (int mm = 0; mm < 4; ++mm) {
          int c = c0 + wm * 64 + mm * 16 + h;
          float val = (acc[mm][nn][r] + bias[c]) * escale;
          if (epi == 1) {
            int d = D0 + mm;
            ((u16*)Out)[((b * 16 + h) * 64 + d) * 1024 + n] = f2bf(val);
          } else {
            ((float*)Out)[(b << 20) + (size_t)c * 1024 + n] = val;
          }
        }
      }
    }
  }
}

template <int EPI>
__global__ __launch_bounds__(256, 2) void gemm4b(const u16* __restrict__ A,
                                                 const u16* __restrict__ B,
                                                 const float* __restrict__ bias,
                                                 void* __restrict__ Out, float escale) {
  __shared__ u16 LD[36864];  // 72 KB
  gemm_body(A, B, bias, Out, escale, EPI, LD);
}

// ---------------------------------------------------------------------------
// Split-K GEMM body (r22 + rule-#20 fix): tile 256(M)x128(N), BK=64,
// 8 waves = 2M x 2N x 2K. Each wave: 128x64 sub-tile over half of K.
// 3 LDS buffers (144 KB), 1 barrier + vmcnt(6) per K-tile. The epilogue
// exchange/store now uses ONLY compile-time acc indices (static branches on
// kkw) -- r22's runtime-indexed acc[m][2*kkw+p] demoted acc to scratch
// (WRITE_SIZE 382 MB, VGPR 100), which was the entire regression.
// epi 0: bf16 -> Q/K [ng][h][d]; 1: bf16 -> V [b][h][d][n]; 2: fp32 [b][c][n].
// grid 256 x 512 threads per slice.
// ---------------------------------------------------------------------------
__device__ __forceinline__ void gemm_kk_body(const u16* __restrict__ A,
                                             const u16* __restrict__ B,
                                             const float* __restrict__ bias,
                                             void* __restrict__ Out, float escale,
                                             int epi, u16* LD) {
  int tid = threadIdx.x;
  int wave = tid >> 6, l = tid & 63, ln = l & 15, g = l >> 4;
  int kkw = wave & 1, wn = (wave >> 1) & 1, wm = wave >> 2;
  int bid = blockIdx.x;
  int j = bid >> 3;
  int mt = j & 3;
  int nt = (bid & 7) * 8 + (j >> 2);
  int c0 = mt * 256, n0 = nt * 128;

  // staging: thread -> row r0 (+64/128/192 for A, +64 for B), swizzled 16B col
  int r0 = tid >> 3, sl = tid & 7;
  int scol = (sl ^ (r0 & 7)) * 8;
  const u16* aS = A + (size_t)(c0 + r0) * 1024 + scol;
  const u16* bS = B + (size_t)(n0 + r0) * 1024 + scol;
  int dst0 = tid * 8;

  // fragment reads: row X, slot (kkw*4+g) ^ (X&7); X&7 == ln&7 for our rows
  int swr = (((kkw << 2) | g) ^ (ln & 7)) * 8;
  int laneA = (wm * 128 + ln) * 64 + swr;   // + m*1024 + bufA*16384
  int laneB = (wn * 64 + ln) * 64 + swr;    // + nn*1024 + 49152 + bufB*8192

  f32x4 acc[8][4] = {};

#define STGA(kt, buf)                                                     \
  do {                                                                    \
    const u16* s_ = aS + (kt) * 64;                                       \
    int d_ = (buf) * 16384 + dst0;                                        \
    gload_lds16(s_, &LD[d_]);                                             \
    gload_lds16(s_ + 65536, &LD[d_ + 4096]);                              \
    gload_lds16(s_ + 131072, &LD[d_ + 8192]);                             \
    gload_lds16(s_ + 196608, &LD[d_ + 12288]);                            \
  } while (0)
#define STGB(kt, buf)                                                     \
  do {                                                                    \
    const u16* s_ = bS + (kt) * 64;                                       \
    int d_ = 49152 + (buf) * 8192 + dst0;                                 \
    gload_lds16(s_, &LD[d_]);                                             \
    gload_lds16(s_ + 65536, &LD[d_ + 4096]);                              \
  } while (0)

  // prologue: tiles 0 and 1 (12 loads)
  STGA(0, 0);
  STGB(0, 0);
  STGA(1, 1);
  STGB(1, 1);

#pragma unroll
  for (int t = 0; t < 16; ++t) {
    if (t < 15)
      asm volatile("s_waitcnt vmcnt(6)" ::: "memory");
    else
      asm volatile("s_waitcnt vmcnt(0)" ::: "memory");
    asm volatile("s_barrier" ::: "memory");
    const int ab = (t % 3) * 16384;
    const int bb = 49152 + (t % 3) * 8192;
    bf16x8 af[4], bfr[4];
    // phase 0: m 0-3
#pragma unroll
    for (int m = 0; m < 4; ++m) af[m] = *(const bf16x8*)&LD[ab + laneA + m * 1024];
#pragma unroll
    for (int nn = 0; nn < 4; ++nn) bfr[nn] = *(const bf16x8*)&LD[bb + laneB + nn * 1024];
    if (t <= 13) STGA(t + 2, (t + 2) % 3);
    __builtin_amdgcn_s_setprio(1);
#pragma unroll
    for (int m = 0; m < 4; ++m)
#pragma unroll
      for (int nn = 0; nn < 4; ++nn)
        acc[m][nn] = __builtin_amdgcn_mfma_f32_16x16x32_bf16(af[m], bfr[nn], acc[m][nn], 0, 0, 0);
    __builtin_amdgcn_s_setprio(0);
    // phase 1: m 4-7 (B reused)
#pragma unroll
    for (int m = 0; m < 4; ++m) af[m] = *(const bf16x8*)&LD[ab + laneA + (m + 4) * 1024];
    if (t <= 13) STGB(t + 2, (t + 2) % 3);
    __builtin_amdgcn_s_setprio(1);
#pragma unroll
    for (int m = 0; m < 4; ++m)
#pragma unroll
      for (int nn = 0; nn < 4; ++nn)
        acc[m + 4][nn] = __builtin_amdgcn_mfma_f32_16x16x32_bf16(af[m], bfr[nn], acc[m + 4][nn], 0, 0, 0);
    __builtin_amdgcn_s_setprio(0);
  }
#undef STGA
#undef STGB

  // ---- cross-kk reduction, ALL acc indices compile-time (rule #20) ----
  float* LDf = (float*)LD;
  int mybase = wave * 4160 + l * 65;            // f32 units; stride 65 = bank-free
  int pbase = (wave ^ 1) * 4160 + l * 65;
  __syncthreads();
  if (kkw == 0) {
#pragma unroll
    for (int m = 0; m < 8; ++m) {
      *(f32x4*)&LDf[mybase + (m * 2) * 4] = acc[m][2];
      *(f32x4*)&LDf[mybase + (m * 2 + 1) * 4] = acc[m][3];
    }
  } else {
#pragma unroll
    for (int m = 0; m < 8; ++m) {
      *(f32x4*)&LDf[mybase + (m * 2) * 4] = acc[m][0];
      *(f32x4*)&LDf[mybase + (m * 2 + 1) * 4] = acc[m][1];
    }
  }
  __syncthreads();
  if (kkw == 0) {
#pragma unroll
    for (int m = 0; m < 8; ++m) {
      acc[m][0] += *(const f32x4*)&LDf[pbase + (m * 2) * 4];
      acc[m][1] += *(const f32x4*)&LDf[pbase + (m * 2 + 1) * 4];
    }
  } else {
#pragma unroll
    for (int m = 0; m < 8; ++m) {
      acc[m][2] += *(const f32x4*)&LDf[pbase + (m * 2) * 4];
      acc[m][3] += *(const f32x4*)&LDf[pbase + (m * 2 + 1) * 4];
    }
  }

  int D0 = (c0 >> 4) + wm * 8;
#define EPIST(NNACC, NN)                                                  \
  do {                                                                    \
    size_t ng = (size_t)n0 + wn * 64 + (NN) * 16 + ln;                    \
    _Pragma("unroll") for (int r = 0; r < 4; ++r) {                       \
      int h = g * 4 + r;                                                  \
      if (epi == 0) {                                                     \
        bf16x8 pk;                                                        \
        _Pragma("unroll") for (int m = 0; m < 8; ++m) {                   \
          int c = c0 + wm * 128 + m * 16 + h;                             \
          pk[m] = (__bf16)((acc[m][NNACC][r] + bias[c]) * escale);        \
        }                                                                 \
        *(bf16x8*)((u16*)Out + ng * 1024 + (size_t)h * 64 + D0) = pk;     \
      } else {                                                            \
        size_t b = ng >> 10, n = ng & 1023;                               \
        _Pragma("unroll") for (int m = 0; m < 8; ++m) {                   \
          int c = c0 + wm * 128 + m * 16 + h;                             \
          float val = (acc[m][NNACC][r] + bias[c]) * escale;              \
          if (epi == 1) {                                                 \
            int d = D0 + m;                                               \
            ((u16*)Out)[((b * 16 + h) * 64 + d) * 1024 + n] = f2bf(val);  \
          } else {                                                        \
            ((float*)Out)[(b << 20) + (size_t)c * 1024 + n] = val;        \
          }                                                               \
        }                                                                 \
      }                                                                   \
    }                                                                     \
  } while (0)

  if (kkw == 0) {
    EPIST(0, 0);
    EPIST(1, 1);
  } else {
    EPIST(2, 2);
    EPIST(3, 3);
  }
#undef EPIST
}

// QKV: grid (256, 3) x 512 threads; z selects weight/input/output/epi.
__global__ __launch_bounds__(512, 1) void gemm_qkvs(const u16* __restrict__ Wbf,
                                                    const u16* __restrict__ X3,
                                                    const float* __restrict__ bq,
                                                    const float* __restrict__ bk,
                                                    const float* __restrict__ bv,
                                                    u16* __restrict__ Qh,
                                                    u16* __restrict__ Kh,
                                                    u16* __restrict__ Vt, float qscale) {
  __shared__ u16 LD[73728];  // 144 KB
  int z = blockIdx.y;
  const u16* A = Wbf + ((size_t)z << 20);
  const u16* B = X3 + ((size_t)z << 23);
  const float* bias = (z == 0) ? bq : (z == 1) ? bk : bv;
  void* Out = (z == 0) ? (void*)Qh : (z == 1) ? (void*)Kh : (void*)Vt;
  float escale = (z == 0) ? qscale : 1.0f;
  int epi = (z == 2) ? 1 : 0;
  gemm_kk_body(A, B, bias, Out, escale, epi, LD);
}

// Final projection: grid 256 x 512 threads, epi 2.
__global__ __launch_bounds__(512, 1) void gemm_fs(const u16* __restrict__ A,
                                                  const u16* __restrict__ B,
                                                  const float* __restrict__ bias,
                                                  void* __restrict__ Out) {
  __shared__ u16 LD[73728];  // 144 KB
  gemm_kk_body(A, B, bias, Out, 1.0f, 2, LD);
}

// ---------------------------------------------------------------------------
// Flash attention v5 (r17 winner, unchanged): one block = (b,h, 256 q-rows),
// register-P. Q,K in [b][n][h][d], V in [b][h][d][n]. Output [b][n][h*64+d].
// ---------------------------------------------------------------------------
__global__ __launch_bounds__(256, 2) void attn_kernel(const u16* __restrict__ Qh,
                                                      const u16* __restrict__ Kh,
                                                      const u16* __restrict__ Vt,
                                                      u16* __restrict__ Xh) {
  __shared__ u16 Ks[2][4096];
  __shared__ u16 Vs[2][4096];
  int tid = threadIdx.x;
  int w = tid >> 6, l = tid & 63, ln = l & 15, g = l >> 4;
  int id = blockIdx.x;
  int bh7 = id & 7;
  int qp = (id >> 3) & 3;
  int bh = (id >> 5) * 8 + bh7;
  size_t b = bh >> 4;
  int h = bh & 15;
  const u16* Qg = Qh + (b << 20) + (h << 6);
  const u16* Kg = Kh + (b << 20) + (h << 6);
  const u16* Vg = Vt + ((size_t)bh << 16);
  u16* Og = Xh + (b << 20) + (h << 6);

  bf16x8 qf[4][2];
#pragma unroll
  for (int t = 0; t < 4; ++t)
#pragma unroll
    for (int kk = 0; kk < 2; ++kk)
      qf[t][kk] = *(const bf16x8*)(Qg + (size_t)(qp * 256 + t * 64 + w * 16 + ln) * 1024 + kk * 32 + g * 8);

  int lr = l >> 3;
  int sw8 = ((l & 7) ^ lr) << 3;
  int r0 = w * 16 + lr, r1 = r0 + 8;
  const u16* kS0 = Kg + (size_t)r0 * 1024 + sw8;
  const u16* kS1 = Kg + (size_t)r1 * 1024 + sw8;
  const u16* vS0 = Vg + (size_t)r0 * 1024 + sw8;
  const u16* vS1 = Vg + (size_t)r1 * 1024 + sw8;

  f32x4 xacc[4][4] = {};
  float lacc[4] = {0.f, 0.f, 0.f, 0.f};

  gload_lds16(kS0, &Ks[0][(w * 2) * 512]);
  gload_lds16(kS1, &Ks[0][(w * 2 + 1) * 512]);
  gload_lds16(vS0, &Vs[0][(w * 2) * 512]);
  gload_lds16(vS1, &Vs[0][(w * 2 + 1) * 512]);
  __syncthreads();

  int sx = ln & 7;
  int cur = 0;
  for (int kt = 0; kt < 16; ++kt) {
    if (kt < 15) {
      int nxt = cur ^ 1;
      gload_lds16(kS0 + (size_t)(kt + 1) * 65536, &Ks[nxt][(w * 2) * 512]);
      gload_lds16(kS1 + (size_t)(kt + 1) * 65536, &Ks[nxt][(w * 2 + 1) * 512]);
      gload_lds16(vS0 + (kt + 1) * 64, &Vs[nxt][(w * 2) * 512]);
      gload_lds16(vS1 + (kt + 1) * 64, &Vs[nxt][(w * 2 + 1) * 512]);
    }
    bf16x8 kf[2][4];
#pragma unroll
    for (int kk = 0; kk < 2; ++kk)
#pragma unroll
      for (int f = 0; f < 4; ++f) {
        int slot = (((kk << 2) + g) ^ sx) << 3;
        kf[kk][f] = *(const bf16x8*)&Ks[cur][(f * 16 + ln) * 64 + slot];
      }
    bf16x8 vf[2][4];
#pragma unroll
    for (int kk = 0; kk < 2; ++kk) {
      int s0 = (kk << 2) + (g >> 1);
      int off = (g & 1) << 2;
#pragma unroll
      for (int fd = 0; fd < 4; ++fd) {
        int rowb = (fd * 16 + ln) * 64;
        bfu uv;
        uv.v4[0] = *(const bf16x4*)&Vs[cur][rowb + ((s0 ^ sx) << 3) + off];
        uv.v4[1] = *(const bf16x4*)&Vs[cur][rowb + (((s0 + 2) ^ sx) << 3) + off];
        vf[kk][fd] = uv.v8;
      }
    }
#pragma unroll
    for (int t = 0; t < 4; ++t) {
      f32x4 sacc[4] = {};
#pragma unroll
      for (int kk = 0; kk < 2; ++kk)
#pragma unroll
        for (int f = 0; f < 4; ++f)
          sacc[f] = __builtin_amdgcn_mfma_f32_16x16x32_bf16(kf[kk][f], qf[t][kk], sacc[f], 0, 0, 0);
      bf16x8 pf[2];
#pragma unroll
      for (int kk = 0; kk < 2; ++kk) {
        bfu up;
#pragma unroll
        for (int e2 = 0; e2 < 2; ++e2) {
          int f = 2 * kk + e2;
          float p0 = __builtin_amdgcn_exp2f(sacc[f][0]);
          float p1 = __builtin_amdgcn_exp2f(sacc[f][1]);
          float p2 = __builtin_amdgcn_exp2f(sacc[f][2]);
          float p3 = __builtin_amdgcn_exp2f(sacc[f][3]);
          lacc[t] += (p0 + p1) + (p2 + p3);
          bf16x4 pb;
          pb[0] = (__bf16)p0; pb[1] = (__bf16)p1; pb[2] = (__bf16)p2; pb[3] = (__bf16)p3;
          up.v4[e2] = pb;
        }
        pf[kk] = up.v8;
      }
#pragma unroll
      for (int kk = 0; kk < 2; ++kk)
#pragma unroll
        for (int fd = 0; fd < 4; ++fd)
          xacc[t][fd] = __builtin_amdgcn_mfma_f32_16x16x32_bf16(pf[kk], vf[kk][fd], xacc[t][fd], 0, 0, 0);
    }
    __syncthreads();
    cur ^= 1;
  }

#pragma unroll
  for (int t = 0; t < 4; ++t) {
    float lt = lacc[t];
    lt += __shfl_xor(lt, 16);
    lt += __shfl_xor(lt, 32);
    float il[4];
#pragma unroll
    for (int r = 0; r < 4; ++r) il[r] = 1.0f / __shfl(lt, g * 4 + r);
#pragma unroll
    for (int fd = 0; fd < 4; ++fd)
#pragma unroll
      for (int r = 0; r < 4; ++r) {
        int nq = qp * 256 + t * 64 + w * 16 + g * 4 + r;
        Og[(size_t)nq * 1024 + fd * 16 + ln] = f2bf(xacc[t][fd][r] * il[r]);
      }
  }
}

// ---------------------------------------------------------------------------
extern "C" void kernel_launch(void* const* d_in, const int* in_sizes, int n_in,
                              void* d_out, int out_size, void* d_ws, size_t ws_size,
                              hipStream_t stream) {
  const float* q  = (const float*)d_in[0];
  const float* k  = (const float*)d_in[1];
  const float* v  = (const float*)d_in[2];
  const float* Wq = (const float*)d_in[3];
  const float* bq = (const float*)d_in[4];
  const float* Wk = (const float*)d_in[5];
  const float* bk = (const float*)d_in[6];
  const float* Wv = (const float*)d_in[7];
  const float* bv = (const float*)d_in[8];
  const float* Wm = (const float*)d_in[9];
  const float* bm = (const float*)d_in[10];

  char* ws = (char*)d_ws;
  u16* Wbf = (u16*)ws;                      //  8 MB: Wq,Wk,Wv,Wm' bf16
  u16* Qh  = (u16*)(ws + (8ull << 20));     // 16 MB [b][n][h][d]
  u16* Kh  = (u16*)(ws + (24ull << 20));    // 16 MB [b][n][h][d]
  u16* Vt  = (u16*)(ws + (40ull << 20));    // 16 MB [b][h][d][n]
  u16* X3  = (u16*)(ws + (56ull << 20));    // 16 or 48 MB (X^T bufs; attn out)

  cast_weights<<<dim3(1024, 4, 1), 256, 0, stream>>>(Wq, Wk, Wv, Wm, Wbf);

  const float qscale = 0.125f * 1.44269504088896340736f;  // 1/sqrt(64) * log2(e)

  if (ws_size >= (104ull << 20)) {
    transpose_cast3<<<dim3(16, 16, 24), 256, 0, stream>>>(q, k, v, X3);
    gemm_qkvs<<<dim3(256, 3), 512, 0, stream>>>(Wbf, X3, bq, bk, bv, Qh, Kh, Vt, qscale);
    attn_kernel<<<512, 256, 0, stream>>>(Qh, Kh, Vt, X3);
    gemm_fs<<<256, 512, 0, stream>>>(Wbf + (3u << 20), X3, bm, d_out);
  } else {
    dim3 tg(16, 16, 8);
    transpose_cast<<<tg, 256, 0, stream>>>(q, X3);
    gemm4b<0><<<256, 256, 0, stream>>>(Wbf, X3, bq, Qh, qscale);
    transpose_cast<<<tg, 256, 0, stream>>>(k, X3);
    gemm4b<0><<<256, 256, 0, stream>>>(Wbf + (1u << 20), X3, bk, Kh, 1.0f);
    transpose_cast<<<tg, 256, 0, stream>>>(v, X3);
    gemm4b<1><<<256, 256, 0, stream>>>(Wbf + (2u << 20), X3, bv, Vt, 1.0f);
    attn_kernel<<<512, 256, 0, stream>>>(Qh, Kh, Vt, X3);
    gemm4b<2><<<256, 256, 0, stream>>>(Wbf + (3u << 20), X3, bm, d_out, 1.0f);
  }
}

// Round 24
// 164.445 us; speedup vs baseline: 1.6732x; 1.1110x over previous
//
#include <hip/hip_runtime.h>

typedef __bf16 bf16x8 __attribute__((ext_vector_type(8)));
typedef __bf16 bf16x4 __attribute__((ext_vector_type(4)));
typedef float f32x4 __attribute__((ext_vector_type(4)));
typedef unsigned short u16;
typedef unsigned int u32;

typedef union { bf16x8 v8; bf16x4 v4[2]; } bfu;

__device__ __forceinline__ u16 f2bf(float f) {
  u32 u = __builtin_bit_cast(u32, f);
  u = (u + 0x7FFFu + ((u >> 16) & 1u)) >> 16;
  return (u16)u;
}

__device__ __forceinline__ void gload_lds16(const void* g, void* l) {
  __builtin_amdgcn_global_load_lds((const __attribute__((address_space(1))) void*)g,
                                   (__attribute__((address_space(3))) void*)l, 16, 0, 0);
}

// ---------------------------------------------------------------------------
// Transpose + cast (batched): z = b(0..7) | which(0..2)<<3.
// ---------------------------------------------------------------------------
__global__ __launch_bounds__(256) void transpose_cast3(const float* __restrict__ q,
                                                       const float* __restrict__ k,
                                                       const float* __restrict__ v,
                                                       u16* __restrict__ X3) {
  __shared__ float T[64][68];
  int tid = threadIdx.x;
  int n0 = blockIdx.x * 64, i0 = blockIdx.y * 64;
  int z = blockIdx.z;
  int which = z >> 3, b = z & 7;
  const float* src = (which == 0) ? q : (which == 1) ? k : v;
  size_t boff = (size_t)b << 20;
  const float* s = src + boff;
  u16* d = X3 + ((size_t)which << 23) + boff;
  int ir = tid >> 4, n4 = (tid & 15) * 4;
#pragma unroll
  for (int r = 0; r < 4; ++r) {
    int i_loc = ir + r * 16;
    float4 vv = *(const float4*)(s + (size_t)(i0 + i_loc) * 1024 + n0 + n4);
    *(float4*)&T[i_loc][n4] = vv;
  }
  __syncthreads();
  int nr = tid >> 3, i8 = (tid & 7) * 8;
#pragma unroll
  for (int r = 0; r < 2; ++r) {
    int n_loc = nr + r * 32;
    u32 pk[4];
#pragma unroll
    for (int j = 0; j < 4; ++j) {
      float f0 = T[i8 + 2 * j][n_loc];
      float f1 = T[i8 + 2 * j + 1][n_loc];
      pk[j] = (u32)f2bf(f0) | ((u32)f2bf(f1) << 16);
    }
    *(uint4*)(d + (size_t)(n0 + n_loc) * 1024 + i0 + i8) = make_uint4(pk[0], pk[1], pk[2], pk[3]);
  }
}

__global__ __launch_bounds__(256) void transpose_cast(const float* __restrict__ src,
                                                      u16* __restrict__ dst) {
  __shared__ float T[64][68];
  int tid = threadIdx.x;
  int n0 = blockIdx.x * 64, i0 = blockIdx.y * 64;
  size_t boff = (size_t)blockIdx.z << 20;
  const float* s = src + boff;
  u16* d = dst + boff;
  int ir = tid >> 4, n4 = (tid & 15) * 4;
#pragma unroll
  for (int r = 0; r < 4; ++r) {
    int i_loc = ir + r * 16;
    float4 v = *(const float4*)(s + (size_t)(i0 + i_loc) * 1024 + n0 + n4);
    *(float4*)&T[i_loc][n4] = v;
  }
  __syncthreads();
  int nr = tid >> 3, i8 = (tid & 7) * 8;
#pragma unroll
  for (int r = 0; r < 2; ++r) {
    int n_loc = nr + r * 32;
    u32 pk[4];
#pragma unroll
    for (int j = 0; j < 4; ++j) {
      float f0 = T[i8 + 2 * j][n_loc];
      float f1 = T[i8 + 2 * j + 1][n_loc];
      pk[j] = (u32)f2bf(f0) | ((u32)f2bf(f1) << 16);
    }
    *(uint4*)(d + (size_t)(n0 + n_loc) * 1024 + i0 + i8) = make_uint4(pk[0], pk[1], pk[2], pk[3]);
  }
}

// ---------------------------------------------------------------------------
// Cast weights to bf16. w=0..2: Wq/Wk/Wv as-is. w=3: Wm' column-permuted.
// ---------------------------------------------------------------------------
__global__ __launch_bounds__(256) void cast_weights(const float* __restrict__ Wq,
                                                    const float* __restrict__ Wk,
                                                    const float* __restrict__ Wv,
                                                    const float* __restrict__ Wm,
                                                    u16* __restrict__ out) {
  int w = blockIdx.y;
  const float* src = (w == 0) ? Wq : (w == 1) ? Wk : (w == 2) ? Wv : Wm;
  u16* dst = out + ((size_t)w << 20);
  int o = blockIdx.x;
  int c4 = threadIdx.x * 4;
  float f[4];
  if (w < 3) {
    float4 v = *(const float4*)(src + (size_t)o * 1024 + c4);
    f[0] = v.x; f[1] = v.y; f[2] = v.z; f[3] = v.w;
  } else {
#pragma unroll
    for (int j = 0; j < 4; ++j) {
      int cp = c4 + j;
      f[j] = src[(size_t)o * 1024 + (cp & 63) * 16 + (cp >> 6)];
    }
  }
  u32 p0 = (u32)f2bf(f[0]) | ((u32)f2bf(f[1]) << 16);
  u32 p1 = (u32)f2bf(f[2]) | ((u32)f2bf(f[3]) << 16);
  *(uint2*)(dst + (size_t)o * 1024 + c4) = make_uint2(p0, p1);
}

// ---------------------------------------------------------------------------
// GEMM (r18, fallback path only): 4 waves 64x128, 3-buffer, 1 barrier/step,
// counted vmcnt. BM=128, BN=256, BK=32. 72 KB LDS.
// ---------------------------------------------------------------------------
__device__ __forceinline__ void gemm_body(const u16* __restrict__ A,
                                          const u16* __restrict__ B,
                                          const float* __restrict__ bias,
                                          void* __restrict__ Out, float escale,
                                          int epi, u16* LD) {
  int tid = threadIdx.x;
  int wave = tid >> 6, l = tid & 63, ln = l & 15, g = l >> 4;
  int wm = wave >> 1, wn = wave & 1;
  int bid = blockIdx.x;
  int mt = (bid >> 3) & 7;
  int nt = ((bid & 7) << 2) | (bid >> 6);
  int c0 = mt * 128, n0 = nt * 256;

  int R = tid >> 3;
  int v = (tid & 7) ^ (R & 7);
  const u16* aS = A + (size_t)(c0 + 2 * R + (v >> 2)) * 1024 + (v & 3) * 8;
  const u16* bS = B + (size_t)(n0 + 2 * R + (v >> 2)) * 1024 + (v & 3) * 8;

  int slr = ((((ln & 1) << 2) | g) ^ ((ln >> 1) & 7)) * 8;
  int laneA = (wm * 32 + (ln >> 1)) * 64 + slr;
  int laneB = (wn * 64 + (ln >> 1)) * 64 + slr;

  f32x4 acc[4][8] = {};

#define STAGE(buf, kt)                                                        \
  do {                                                                        \
    gload_lds16(aS + (kt) * 32, &LD[(buf) * 4096 + tid * 8]);                 \
    gload_lds16(aS + 65536 + (kt) * 32, &LD[(buf) * 4096 + 2048 + tid * 8]);  \
    gload_lds16(bS + (kt) * 32, &LD[12288 + (buf) * 8192 + tid * 8]);         \
    gload_lds16(bS + 65536 + (kt) * 32,                                       \
                &LD[12288 + (buf) * 8192 + 2048 + tid * 8]);                  \
    gload_lds16(bS + 131072 + (kt) * 32,                                      \
                &LD[12288 + (buf) * 8192 + 4096 + tid * 8]);                  \
    gload_lds16(bS + 196608 + (kt) * 32,                                      \
                &LD[12288 + (buf) * 8192 + 6144 + tid * 8]);                  \
  } while (0)

  STAGE(0, 0);
  STAGE(1, 1);

#pragma unroll
  for (int t = 0; t < 32; ++t) {
    if (t < 31)
      asm volatile("s_waitcnt vmcnt(6)" ::: "memory");
    else
      asm volatile("s_waitcnt vmcnt(0)" ::: "memory");
    asm volatile("s_barrier" ::: "memory");
    if (t <= 29) STAGE((t + 2) % 3, t + 2);
    const int ab = (t % 3) * 4096;
    const int bb = 12288 + (t % 3) * 8192;
    bf16x8 af[4];
#pragma unroll
    for (int mm = 0; mm < 4; ++mm) af[mm] = *(const bf16x8*)&LD[ab + laneA + mm * 512];
    __builtin_amdgcn_s_setprio(1);
#pragma unroll
    for (int nn = 0; nn < 8; ++nn) {
      bf16x8 bfr = *(const bf16x8*)&LD[bb + laneB + nn * 512];
#pragma unroll
      for (int mm = 0; mm < 4; ++mm)
        acc[mm][nn] = __builtin_amdgcn_mfma_f32_16x16x32_bf16(af[mm], bfr, acc[mm][nn], 0, 0, 0);
    }
    __builtin_amdgcn_s_setprio(0);
  }
#undef STAGE

  int D0 = (c0 >> 4) + wm * 4;
#pragma unroll
  for (int nn = 0; nn < 8; ++nn) {
    size_t ng = (size_t)n0 + wn * 128 + nn * 16 + ln;
#pragma unroll
    for (int r = 0; r < 4; ++r) {
      int h = g * 4 + r;
      if (epi == 0) {
        bf16x4 pk;
#pragma unroll
        for (int mm = 0; mm < 4; ++mm) {
          int c = c0 + wm * 64 + mm * 16 + h;
          pk[mm] = (__bf16)((acc[mm][nn][r] + bias[c]) * escale);
        }
        *(bf16x4*)((u16*)Out + ng * 1024 + (size_t)h * 64 + D0) = pk;
      } else {
        size_t b = ng >> 10, n = ng & 1023;
#pragma unroll
        for (int mm = 0; mm < 4; ++mm) {
          int c = c0 + wm * 64 + mm * 16 + h;
          float val = (acc[mm][nn][r] + bias[c]) * escale;
          if (epi == 1) {
            int d = D0 + mm;
            ((u16*)Out)[((b * 16 + h) * 64 + d) * 1024 + n] = f2bf(val);
          } else {
            ((float*)Out)[(b << 20) + (size_t)c * 1024 + n] = val;
          }
        }
      }
    }
  }
}

template <int EPI>
__global__ __launch_bounds__(256, 2) void gemm4b(const u16* __restrict__ A,
                                                 const u16* __restrict__ B,
                                                 const float* __restrict__ bias,
                                                 void* __restrict__ Out, float escale) {
  __shared__ u16 LD[36864];  // 72 KB
  gemm_body(A, B, bias, Out, escale, EPI, LD);
}

// ---------------------------------------------------------------------------
// 8-phase GEMM body v2 (r21 winner): tile 256(M)x128(N), BK=64,
// 8 waves (2M x 4N, wave-tile 128x32, acc[8][2]). LDS 96 KB:
//   A units: buf*16384 + kk*8192  (unit = 256 rows x 32 u16 = 16 KB)
//   B units: 32768 + buf*8192 + kk*4096 (unit = 128 x 32 = 8 KB)
// Per K-tile 4 phases split by (kk, m-half); B-frags reused across m-halves.
// Staging 6 loads/tile (A 2+2, B 1+1) in stream order -> symmetric vmcnt(3)
// at p0/p2 gates (vmcnt(0) only at last tile). Blocks/slice = 4mt x 64nt =
// 256 = exactly one generation per CU.
// XCD map: xcd=bid&7 owns 8 contiguous nt (B 2MB) x all mt (A 2MB) ~ L2.
// epi 0: bf16 -> Q/K [ng][h][d]; 1: bf16 -> V [b][h][d][n]; 2: fp32 [b][c][n].
// ---------------------------------------------------------------------------
__device__ __forceinline__ void gemm8_body(const u16* __restrict__ A,
                                           const u16* __restrict__ B,
                                           const float* __restrict__ bias,
                                           void* __restrict__ Out, float escale,
                                           int epi, u16* LD) {
  int tid = threadIdx.x;
  int wave = tid >> 6, l = tid & 63, ln = l & 15, g = l >> 4;
  int wm = wave >> 2, wn = wave & 3;
  int bid = blockIdx.x;
  int j = bid >> 3;
  int mt = j & 3;
  int nt = (bid & 7) * 8 + (j >> 2);
  int c0 = mt * 256, n0 = nt * 128;

  int r0 = tid >> 2;
  int sw = ((tid & 3) ^ ((tid >> 3) & 3)) * 8;
  const u16* aS = A + (size_t)(c0 + r0) * 1024 + sw;
  const u16* bS = B + (size_t)(n0 + r0 % 128) * 1024 + sw;
  int dst0 = tid * 8;

  int swr = (g ^ ((ln >> 1) & 3)) * 8;
  int laneA = (wm * 128 + ln) * 32 + swr;           // + m*512 + buf*16384 + kk*8192
  int laneB = 32768 + (wn * 32 + ln) * 32 + swr;    // + nn*512 + buf*8192 + kk*4096

  f32x4 acc[8][2] = {};

#define SUA(kkv, kt, buf)                                                 \
  do {                                                                    \
    const u16* s_ = aS + (kt) * 64 + (kkv) * 32;                          \
    int d_ = (buf) * 16384 + (kkv) * 8192 + dst0;                         \
    gload_lds16(s_, &LD[d_]);                                             \
    gload_lds16(s_ + 131072, &LD[d_ + 4096]);                             \
  } while (0)
#define SUB(kkv, kt, buf)                                                 \
  do {                                                                    \
    gload_lds16(bS + (kt) * 64 + (kkv) * 32,                              \
                &LD[32768 + (buf) * 8192 + (kkv) * 4096 + dst0]);         \
  } while (0)

  // prologue: tile 0, stream order Akk0, Bkk0, Akk1, Bkk1 (6 loads)
  SUA(0, 0, 0);
  SUB(0, 0, 0);
  SUA(1, 0, 0);
  SUB(1, 0, 0);

#pragma unroll
  for (int kt = 0; kt < 16; ++kt) {
    const int buf = kt & 1;
    const int ab = buf * 16384;
    const int bb = buf * 8192;
    bf16x8 af[4], bf0[2];
    // ---- phase 0: kk0, m 0-3 ----
    asm volatile("s_waitcnt vmcnt(3)" ::: "memory");
    asm volatile("s_barrier" ::: "memory");
#pragma unroll
    for (int m = 0; m < 4; ++m) af[m] = *(const bf16x8*)&LD[ab + laneA + m * 512];
#pragma unroll
    for (int nn = 0; nn < 2; ++nn) bf0[nn] = *(const bf16x8*)&LD[bb + laneB + nn * 512];
    if (kt < 15) SUA(0, kt + 1, buf ^ 1);
    __builtin_amdgcn_s_setprio(1);
#pragma unroll
    for (int m = 0; m < 4; ++m)
#pragma unroll
      for (int nn = 0; nn < 2; ++nn)
        acc[m][nn] = __builtin_amdgcn_mfma_f32_16x16x32_bf16(af[m], bf0[nn], acc[m][nn], 0, 0, 0);
    __builtin_amdgcn_s_setprio(0);
    // ---- phase 1: kk0, m 4-7 (B reused) ----
#pragma unroll
    for (int m = 0; m < 4; ++m) af[m] = *(const bf16x8*)&LD[ab + laneA + (m + 4) * 512];
    if (kt < 15) SUB(0, kt + 1, buf ^ 1);
    __builtin_amdgcn_s_setprio(1);
#pragma unroll
    for (int m = 0; m < 4; ++m)
#pragma unroll
      for (int nn = 0; nn < 2; ++nn)
        acc[m + 4][nn] = __builtin_amdgcn_mfma_f32_16x16x32_bf16(af[m], bf0[nn], acc[m + 4][nn], 0, 0, 0);
    __builtin_amdgcn_s_setprio(0);
    // ---- phase 2: kk1, m 0-3 ----
    if (kt < 15)
      asm volatile("s_waitcnt vmcnt(3)" ::: "memory");
    else
      asm volatile("s_waitcnt vmcnt(0)" ::: "memory");
    asm volatile("s_barrier" ::: "memory");
#pragma unroll
    for (int m = 0; m < 4; ++m) af[m] = *(const bf16x8*)&LD[ab + 8192 + laneA + m * 512];
#pragma unroll
    for (int nn = 0; nn < 2; ++nn) bf0[nn] = *(const bf16x8*)&LD[bb + 4096 + laneB + nn * 512];
    if (kt < 15) SUA(1, kt + 1, buf ^ 1);
    __builtin_amdgcn_s_setprio(1);
#pragma unroll
    for (int m = 0; m < 4; ++m)
#pragma unroll
      for (int nn = 0; nn < 2; ++nn)
        acc[m][nn] = __builtin_amdgcn_mfma_f32_16x16x32_bf16(af[m], bf0[nn], acc[m][nn], 0, 0, 0);
    __builtin_amdgcn_s_setprio(0);
    // ---- phase 3: kk1, m 4-7 ----
#pragma unroll
    for (int m = 0; m < 4; ++m) af[m] = *(const bf16x8*)&LD[ab + 8192 + laneA + (m + 4) * 512];
    if (kt < 15) SUB(1, kt + 1, buf ^ 1);
    __builtin_amdgcn_s_setprio(1);
#pragma unroll
    for (int m = 0; m < 4; ++m)
#pragma unroll
      for (int nn = 0; nn < 2; ++nn)
        acc[m + 4][nn] = __builtin_amdgcn_mfma_f32_16x16x32_bf16(af[m], bf0[nn], acc[m + 4][nn], 0, 0, 0);
    __builtin_amdgcn_s_setprio(0);
  }
#undef SUA
#undef SUB

  int D0 = (c0 >> 4) + wm * 8;
#pragma unroll
  for (int nn = 0; nn < 2; ++nn) {
    size_t ng = (size_t)n0 + wn * 32 + nn * 16 + ln;
#pragma unroll
    for (int r = 0; r < 4; ++r) {
      int h = g * 4 + r;
      if (epi == 0) {
        bf16x8 pk;
#pragma unroll
        for (int m = 0; m < 8; ++m) {
          int c = c0 + wm * 128 + m * 16 + h;
          pk[m] = (__bf16)((acc[m][nn][r] + bias[c]) * escale);
        }
        *(bf16x8*)((u16*)Out + ng * 1024 + (size_t)h * 64 + D0) = pk;
      } else {
        size_t b = ng >> 10, n = ng & 1023;
#pragma unroll
        for (int m = 0; m < 8; ++m) {
          int c = c0 + wm * 128 + m * 16 + h;
          float val = (acc[m][nn][r] + bias[c]) * escale;
          if (epi == 1) {
            int d = D0 + m;
            ((u16*)Out)[((b * 16 + h) * 64 + d) * 1024 + n] = f2bf(val);
          } else {
            ((float*)Out)[(b << 20) + (size_t)c * 1024 + n] = val;
          }
        }
      }
    }
  }
}

// QKV: grid (256, 3) x 512 threads; z selects weight/input/output/epi.
__global__ __launch_bounds__(512, 1) void gemm_qkv8(const u16* __restrict__ Wbf,
                                                    const u16* __restrict__ X3,
                                                    const float* __restrict__ bq,
                                                    const float* __restrict__ bk,
                                                    const float* __restrict__ bv,
                                                    u16* __restrict__ Qh,
                                                    u16* __restrict__ Kh,
                                                    u16* __restrict__ Vt, float qscale) {
  __shared__ u16 LD[49152];  // 96 KB
  int z = blockIdx.y;
  const u16* A = Wbf + ((size_t)z << 20);
  const u16* B = X3 + ((size_t)z << 23);
  const float* bias = (z == 0) ? bq : (z == 1) ? bk : bv;
  void* Out = (z == 0) ? (void*)Qh : (z == 1) ? (void*)Kh : (void*)Vt;
  float escale = (z == 0) ? qscale : 1.0f;
  int epi = (z == 2) ? 1 : 0;
  gemm8_body(A, B, bias, Out, escale, epi, LD);
}

// Final projection: grid 256 x 512 threads, epi 2.
__global__ __launch_bounds__(512, 1) void gemm8f(const u16* __restrict__ A,
                                                 const u16* __restrict__ B,
                                                 const float* __restrict__ bias,
                                                 void* __restrict__ Out) {
  __shared__ u16 LD[49152];  // 96 KB
  gemm8_body(A, B, bias, Out, 1.0f, 2, LD);
}

// ---------------------------------------------------------------------------
// Flash attention v5 (r17 winner, unchanged): one block = (b,h, 256 q-rows),
// register-P. Q,K in [b][n][h][d], V in [b][h][d][n]. Output [b][n][h*64+d].
// ---------------------------------------------------------------------------
__global__ __launch_bounds__(256, 2) void attn_kernel(const u16* __restrict__ Qh,
                                                      const u16* __restrict__ Kh,
                                                      const u16* __restrict__ Vt,
                                                      u16* __restrict__ Xh) {
  __shared__ u16 Ks[2][4096];
  __shared__ u16 Vs[2][4096];
  int tid = threadIdx.x;
  int w = tid >> 6, l = tid & 63, ln = l & 15, g = l >> 4;
  int id = blockIdx.x;
  int bh7 = id & 7;
  int qp = (id >> 3) & 3;
  int bh = (id >> 5) * 8 + bh7;
  size_t b = bh >> 4;
  int h = bh & 15;
  const u16* Qg = Qh + (b << 20) + (h << 6);
  const u16* Kg = Kh + (b << 20) + (h << 6);
  const u16* Vg = Vt + ((size_t)bh << 16);
  u16* Og = Xh + (b << 20) + (h << 6);

  bf16x8 qf[4][2];
#pragma unroll
  for (int t = 0; t < 4; ++t)
#pragma unroll
    for (int kk = 0; kk < 2; ++kk)
      qf[t][kk] = *(const bf16x8*)(Qg + (size_t)(qp * 256 + t * 64 + w * 16 + ln) * 1024 + kk * 32 + g * 8);

  int lr = l >> 3;
  int sw8 = ((l & 7) ^ lr) << 3;
  int r0 = w * 16 + lr, r1 = r0 + 8;
  const u16* kS0 = Kg + (size_t)r0 * 1024 + sw8;
  const u16* kS1 = Kg + (size_t)r1 * 1024 + sw8;
  const u16* vS0 = Vg + (size_t)r0 * 1024 + sw8;
  const u16* vS1 = Vg + (size_t)r1 * 1024 + sw8;

  f32x4 xacc[4][4] = {};
  float lacc[4] = {0.f, 0.f, 0.f, 0.f};

  gload_lds16(kS0, &Ks[0][(w * 2) * 512]);
  gload_lds16(kS1, &Ks[0][(w * 2 + 1) * 512]);
  gload_lds16(vS0, &Vs[0][(w * 2) * 512]);
  gload_lds16(vS1, &Vs[0][(w * 2 + 1) * 512]);
  __syncthreads();

  int sx = ln & 7;
  int cur = 0;
  for (int kt = 0; kt < 16; ++kt) {
    if (kt < 15) {
      int nxt = cur ^ 1;
      gload_lds16(kS0 + (size_t)(kt + 1) * 65536, &Ks[nxt][(w * 2) * 512]);
      gload_lds16(kS1 + (size_t)(kt + 1) * 65536, &Ks[nxt][(w * 2 + 1) * 512]);
      gload_lds16(vS0 + (kt + 1) * 64, &Vs[nxt][(w * 2) * 512]);
      gload_lds16(vS1 + (kt + 1) * 64, &Vs[nxt][(w * 2 + 1) * 512]);
    }
    bf16x8 kf[2][4];
#pragma unroll
    for (int kk = 0; kk < 2; ++kk)
#pragma unroll
      for (int f = 0; f < 4; ++f) {
        int slot = (((kk << 2) + g) ^ sx) << 3;
        kf[kk][f] = *(const bf16x8*)&Ks[cur][(f * 16 + ln) * 64 + slot];
      }
    bf16x8 vf[2][4];
#pragma unroll
    for (int kk = 0; kk < 2; ++kk) {
      int s0 = (kk << 2) + (g >> 1);
      int off = (g & 1) << 2;
#pragma unroll
      for (int fd = 0; fd < 4; ++fd) {
        int rowb = (fd * 16 + ln) * 64;
        bfu uv;
        uv.v4[0] = *(const bf16x4*)&Vs[cur][rowb + ((s0 ^ sx) << 3) + off];
        uv.v4[1] = *(const bf16x4*)&Vs[cur][rowb + (((s0 + 2) ^ sx) << 3) + off];
        vf[kk][fd] = uv.v8;
      }
    }
#pragma unroll
    for (int t = 0; t < 4; ++t) {
      f32x4 sacc[4] = {};
#pragma unroll
      for (int kk = 0; kk < 2; ++kk)
#pragma unroll
        for (int f = 0; f < 4; ++f)
          sacc[f] = __builtin_amdgcn_mfma_f32_16x16x32_bf16(kf[kk][f], qf[t][kk], sacc[f], 0, 0, 0);
      bf16x8 pf[2];
#pragma unroll
      for (int kk = 0; kk < 2; ++kk) {
        bfu up;
#pragma unroll
        for (int e2 = 0; e2 < 2; ++e2) {
          int f = 2 * kk + e2;
          float p0 = __builtin_amdgcn_exp2f(sacc[f][0]);
          float p1 = __builtin_amdgcn_exp2f(sacc[f][1]);
          float p2 = __builtin_amdgcn_exp2f(sacc[f][2]);
          float p3 = __builtin_amdgcn_exp2f(sacc[f][3]);
          lacc[t] += (p0 + p1) + (p2 + p3);
          bf16x4 pb;
          pb[0] = (__bf16)p0; pb[1] = (__bf16)p1; pb[2] = (__bf16)p2; pb[3] = (__bf16)p3;
          up.v4[e2] = pb;
        }
        pf[kk] = up.v8;
      }
#pragma unroll
      for (int kk = 0; kk < 2; ++kk)
#pragma unroll
        for (int fd = 0; fd < 4; ++fd)
          xacc[t][fd] = __builtin_amdgcn_mfma_f32_16x16x32_bf16(pf[kk], vf[kk][fd], xacc[t][fd], 0, 0, 0);
    }
    __syncthreads();
    cur ^= 1;
  }

#pragma unroll
  for (int t = 0; t < 4; ++t) {
    float lt = lacc[t];
    lt += __shfl_xor(lt, 16);
    lt += __shfl_xor(lt, 32);
    float il[4];
#pragma unroll
    for (int r = 0; r < 4; ++r) il[r] = 1.0f / __shfl(lt, g * 4 + r);
#pragma unroll
    for (int fd = 0; fd < 4; ++fd)
#pragma unroll
      for (int r = 0; r < 4; ++r) {
        int nq = qp * 256 + t * 64 + w * 16 + g * 4 + r;
        Og[(size_t)nq * 1024 + fd * 16 + ln] = f2bf(xacc[t][fd][r] * il[r]);
      }
  }
}

// ---------------------------------------------------------------------------
extern "C" void kernel_launch(void* const* d_in, const int* in_sizes, int n_in,
                              void* d_out, int out_size, void* d_ws, size_t ws_size,
                              hipStream_t stream) {
  const float* q  = (const float*)d_in[0];
  const float* k  = (const float*)d_in[1];
  const float* v  = (const float*)d_in[2];
  const float* Wq = (const float*)d_in[3];
  const float* bq = (const float*)d_in[4];
  const float* Wk = (const float*)d_in[5];
  const float* bk = (const float*)d_in[6];
  const float* Wv = (const float*)d_in[7];
  const float* bv = (const float*)d_in[8];
  const float* Wm = (const float*)d_in[9];
  const float* bm = (const float*)d_in[10];

  char* ws = (char*)d_ws;
  u16* Wbf = (u16*)ws;                      //  8 MB: Wq,Wk,Wv,Wm' bf16
  u16* Qh  = (u16*)(ws + (8ull << 20));     // 16 MB [b][n][h][d]
  u16* Kh  = (u16*)(ws + (24ull << 20));    // 16 MB [b][n][h][d]
  u16* Vt  = (u16*)(ws + (40ull << 20));    // 16 MB [b][h][d][n]
  u16* X3  = (u16*)(ws + (56ull << 20));    // 16 or 48 MB (X^T bufs; attn out)

  cast_weights<<<dim3(1024, 4, 1), 256, 0, stream>>>(Wq, Wk, Wv, Wm, Wbf);

  const float qscale = 0.125f * 1.44269504088896340736f;  // 1/sqrt(64) * log2(e)

  if (ws_size >= (104ull << 20)) {
    transpose_cast3<<<dim3(16, 16, 24), 256, 0, stream>>>(q, k, v, X3);
    gemm_qkv8<<<dim3(256, 3), 512, 0, stream>>>(Wbf, X3, bq, bk, bv, Qh, Kh, Vt, qscale);
    attn_kernel<<<512, 256, 0, stream>>>(Qh, Kh, Vt, X3);
    gemm8f<<<256, 512, 0, stream>>>(Wbf + (3u << 20), X3, bm, d_out);
  } else {
    dim3 tg(16, 16, 8);
    transpose_cast<<<tg, 256, 0, stream>>>(q, X3);
    gemm4b<0><<<256, 256, 0, stream>>>(Wbf, X3, bq, Qh, qscale);
    transpose_cast<<<tg, 256, 0, stream>>>(k, X3);
    gemm4b<0><<<256, 256, 0, stream>>>(Wbf + (1u << 20), X3, bk, Kh, 1.0f);
    transpose_cast<<<tg, 256, 0, stream>>>(v, X3);
    gemm4b<1><<<256, 256, 0, stream>>>(Wbf + (2u << 20), X3, bv, Vt, 1.0f);
    attn_kernel<<<512, 256, 0, stream>>>(Qh, Kh, Vt, X3);
    gemm4b<2><<<256, 256, 0, stream>>>(Wbf + (3u << 20), X3, bm, d_out, 1.0f);
  }
}